// Round 10
// baseline (263.368 us; speedup 1.0000x reference)
//
#include <hip/hip_runtime.h>

// ---------------- types / helpers ----------------
typedef __attribute__((ext_vector_type(8))) short bf16x8;   // 8 bf16 = 4 VGPR
typedef __attribute__((ext_vector_type(4))) float f32x4;
typedef __attribute__((ext_vector_type(16))) float f32x16;
typedef int v2i __attribute__((ext_vector_type(2)));

union U4B { unsigned u[4]; bf16x8 v; };

__device__ __forceinline__ unsigned short f2bf(float f) {
    union { float f; unsigned u; } v; v.f = f;
    unsigned r = v.u + 0x7fffu + ((v.u >> 16) & 1u);   // RNE
    return (unsigned short)(r >> 16);
}
__device__ __forceinline__ float bf2f(unsigned short s) {
    union { unsigned u; float f; } v; v.u = ((unsigned)s) << 16; return v.f;
}
__device__ __forceinline__ unsigned pkbf(float a, float b) {
    unsigned r;
    asm("v_cvt_pk_bf16_f32 %0, %1, %2" : "=v"(r) : "v"(a), "v"(b));
    return r;
}
// C-frag half (regs base..base+7) -> B-frag of the next layer (verified r3-r8)
__device__ __forceinline__ bf16x8 packhalf(const f32x16& a, int base) {
    unsigned u  = pkbf(a[base + 0], a[base + 1]);
    unsigned u2 = pkbf(a[base + 2], a[base + 3]);
    unsigned v  = pkbf(a[base + 4], a[base + 5]);
    unsigned v2 = pkbf(a[base + 6], a[base + 7]);
    v2i r1 = __builtin_amdgcn_permlane32_swap(u, v, false, false);
    v2i r2 = __builtin_amdgcn_permlane32_swap(u2, v2, false, false);
    U4B b; b.u[0] = r1.x; b.u[1] = r2.x; b.u[2] = r1.y; b.u[3] = r2.y;
    return b.v;
}
__device__ __forceinline__ f32x16 zero16() {
    f32x16 v;
#pragma unroll
    for (int i = 0; i < 16; ++i) v[i] = 0.f;
    return v;
}

// ---------------- problem constants ----------------
#define BATCH   2048
#define TSTEPS  300
#define ROWS_PB 8            // batch rows per main block (16 waves)
// workspace layout (bytes)
#define WM_OFF   0           // 3 * 128*128 bf16 main weights (bias@k=100, carrier n=100)
#define G_OFF    98304       // 2048*128 bf16
#define E_OFF    622592      // 2048*128 bf16 (ends 1146880)
// main-kernel LDS (bytes) — static
#define OFF_X   98304        // 8*128 f32
#define OFF_G   102400
#define OFF_E   106496
#define OFF_P   110592       // 16 f32 wave partials
#define SMEM_M  110656
// fused_pre embed-path LDS (bytes): weight staging 0..114688, then act + biases
#define EACT    114688       // [32][256] bf16 = 16384 (XOR-swizzled act handoff)
#define EB1     131072       // 224 f32
#define EB2     131968       // 224 f32
#define EB3     132864       // 64 f32
#define EC1     133120       // 128 f32
#define SMEM_E  133632

// ---------------- fused pre-pass ----------------
// blocks 0..63  : embedding net (32 batch rows each), staging weights DIRECTLY
//                 from f32 inputs with coalesced reads (consecutive tid =
//                 consecutive source column) + on-the-fly f2bf. Writes g16/e16.
// blocks 64..71 : main-path weight conversion into ws[WM] (bias@k=100 carrier).
__device__ __forceinline__ void act_store(char* act, int l31, int f, int hi,
                                          const f32x16& a) {
#pragma unroll
    for (int r = 0; r < 16; r += 2) {
        int n = 32 * f + (r & 3) + 8 * (r >> 2) + 4 * hi;
        unsigned u = pkbf(fmaxf(a[r], 0.f), fmaxf(a[r + 1], 0.f));   // relu fused
        *(unsigned*)(act + l31 * 512 + ((n * 2) ^ ((l31 & 7) << 4))) = u;
    }
}
__device__ __forceinline__ bf16x8 act_read(const char* act, int l31, int ks, int hi) {
    return *(const bf16x8*)(act + l31 * 512 + ((ks * 32 + hi * 16) ^ ((l31 & 7) << 4)));
}

__global__ __launch_bounds__(256) void fused_pre(
    const float* __restrict__ x,
    const float* __restrict__ W1, const float* __restrict__ b1,
    const float* __restrict__ W2, const float* __restrict__ b2,
    const float* __restrict__ W3, const float* __restrict__ b3,
    const float* __restrict__ U1, const float* __restrict__ c1,
    const float* __restrict__ U2, const float* __restrict__ c2,
    const float* __restrict__ U3, const float* __restrict__ c3,
    const float* __restrict__ U4, const float* __restrict__ c4,
    unsigned char* __restrict__ ws)
{
    __shared__ __align__(16) char sm[SMEM_E];
    const int tid = threadIdx.x;

    if (blockIdx.x >= 64) {
        // ---- main-path weights: 8 blocks x 6144 elements
        const int part = blockIdx.x - 64;
        unsigned short* w16 = (unsigned short*)ws;
        for (int j = part * 6144 + tid; j < (part + 1) * 6144; j += 256) {
            int m = j >> 14, r = j & 16383;
            int k = r >> 7, n = r & 127;      // consecutive tid -> consecutive n (coalesced src)
            float v = 0.f;
            if (m == 2) {
                if (k < 100)       v = U4[k * 128 + n];
                else if (k == 100) v = c4[n];
            } else {
                const float* U = m ? U3 : U2;
                const float* c = m ? c3 : c2;
                if (k < 100)       { if (n < 100) v = U[k * 100 + n]; }
                else if (k == 100) { if (n < 100) v = c[n]; else if (n == 100) v = 1.f; }
            }
            w16[(WM_OFF >> 1) + m * 16384 + n * 128 + k] = f2bf(v);
        }
        return;
    }

    // ================= embedding path (blocks 0..63) =================
    char* act = sm + EACT;
    const int lane = tid & 63, wid = tid >> 6;
    const int l31 = lane & 31, hi = lane >> 5;
    const int brow = blockIdx.x * 32 + l31;   // 32 batch rows per block
    const int sw8 = (l31 & 15) << 4;    // 256B-row weight swizzle
    const int sw9 = (l31 & 31) << 4;    // 512B-row weight swizzle

    // biases -> LDS (direct from inputs; region persists)
    if (tid < 224) ((float*)(sm + EB1))[tid] = (tid < 200) ? b1[tid] : 0.f;
    if (tid < 224) ((float*)(sm + EB2))[tid] = (tid < 200) ? b2[tid] : 0.f;
    if (tid < 64)  ((float*)(sm + EB3))[tid] = b3[tid];
    if (tid < 128) ((float*)(sm + EC1))[tid] = (tid < 100) ? c1[tid] : 0.f;

    // ---- stage A: W1' [224][128] + U1x [128][128]  (direct f32 -> bf16)
    for (int k = 0; k < 128; ++k) {
        if (tid < 224) {
            float v = (tid < 200) ? W1[k * 200 + tid] : 0.f;
            *(unsigned short*)(sm + tid * 256 + ((k * 2) ^ ((tid & 15) << 4))) = f2bf(v);
        }
    }
    for (int kk = 0; kk < 64; ++kk) {
        int k = kk * 2 + (tid >> 7), n = tid & 127;
        float v = (n < 100) ? U1[k * 100 + n] : 0.f;
        *(unsigned short*)(sm + 57344 + n * 256 + ((k * 2) ^ ((n & 15) << 4))) = f2bf(v);
    }

    // x B-frags (all waves: same 32 rows)
    bf16x8 Bx[8];
    {
        const float* xr = x + brow * 128;
#pragma unroll
        for (int ks = 0; ks < 8; ++ks) {
            const int k0 = ks * 16 + hi * 8;
            f32x4 a = *(const f32x4*)(xr + k0);
            f32x4 b = *(const f32x4*)(xr + k0 + 4);
            U4B u;
            u.u[0] = pkbf(a[0], a[1]); u.u[1] = pkbf(a[2], a[3]);
            u.u[2] = pkbf(b[0], b[1]); u.u[3] = pkbf(b[2], b[3]);
            Bx[ks] = u.v;
        }
    }
    __syncthreads();

    unsigned short* g16 = (unsigned short*)(ws + G_OFF);
    unsigned short* e16 = (unsigned short*)(ws + E_OFF);

    // ---- g = x @ U1x (frag = wid) -> global, no bias/relu
    {
        f32x16 ag = zero16();
#pragma unroll
        for (int ks = 0; ks < 8; ++ks) {
            bf16x8 a = *(const bf16x8*)(sm + 57344 + (32 * wid + l31) * 256 + ((ks * 32 + hi * 16) ^ sw8));
            ag = __builtin_amdgcn_mfma_f32_32x32x16_bf16(a, Bx[ks], ag, 0, 0, 0);
        }
#pragma unroll
        for (int r = 0; r < 16; r += 2) {
            int n = 32 * wid + (r & 3) + 8 * (r >> 2) + 4 * hi;
            *(unsigned*)(g16 + brow * 128 + n) = pkbf(ag[r], ag[r + 1]);
        }
    }

    // ---- layer 1: frags {wid, wid+4} of relu(x@W1'+b1) -> act
    for (int f = wid; f < 7; f += 4) {
        f32x16 acc;
#pragma unroll
        for (int r = 0; r < 16; ++r)
            acc[r] = ((float*)(sm + EB1))[32 * f + (r & 3) + 8 * (r >> 2) + 4 * hi];
#pragma unroll
        for (int ks = 0; ks < 8; ++ks) {
            bf16x8 a = *(const bf16x8*)(sm + (32 * f + l31) * 256 + ((ks * 32 + hi * 16) ^ sw8));
            acc = __builtin_amdgcn_mfma_f32_32x32x16_bf16(a, Bx[ks], acc, 0, 0, 0);
        }
        act_store(act, l31, f, hi, acc);
    }
    __syncthreads();

    // ---- read Bh (13 frags) ; stage B: W2' [224][256] direct
    bf16x8 Bh[13];
#pragma unroll
    for (int ks = 0; ks < 13; ++ks) Bh[ks] = act_read(act, l31, ks, hi);
    __syncthreads();   // all layer-1 weight reads done before overwrite
    for (int k = 0; k < 256; ++k) {
        if (tid < 224) {
            float v = (k < 200 && tid < 200) ? W2[k * 200 + tid] : 0.f;
            *(unsigned short*)(sm + tid * 512 + ((k * 2) ^ ((tid & 31) << 4))) = f2bf(v);
        }
    }
    __syncthreads();

    // ---- layer 2: frags {wid, wid+4} of relu(h1@W2'+b2) -> act
    for (int f = wid; f < 7; f += 4) {
        f32x16 acc;
#pragma unroll
        for (int r = 0; r < 16; ++r)
            acc[r] = ((float*)(sm + EB2))[32 * f + (r & 3) + 8 * (r >> 2) + 4 * hi];
#pragma unroll
        for (int ks = 0; ks < 13; ++ks) {
            bf16x8 a = *(const bf16x8*)(sm + (32 * f + l31) * 512 + ((ks * 32 + hi * 16) ^ sw9));
            acc = __builtin_amdgcn_mfma_f32_32x32x16_bf16(a, Bh[ks], acc, 0, 0, 0);
        }
        act_store(act, l31, f, hi, acc);
    }
    __syncthreads();

    // ---- read Bh2 (13 frags) ; stage C: W3' [64][256] + U1h [128][128] direct
    bf16x8 Bh2[13];
#pragma unroll
    for (int ks = 0; ks < 13; ++ks) Bh2[ks] = act_read(act, l31, ks, hi);
    __syncthreads();
    for (int kk = 0; kk < 64; ++kk) {
        int k = kk * 4 + (tid >> 6), n = tid & 63;
        float v = (k < 200) ? W3[k * 64 + n] : 0.f;
        *(unsigned short*)(sm + n * 512 + ((k * 2) ^ ((n & 31) << 4))) = f2bf(v);
    }
    for (int kk = 0; kk < 64; ++kk) {
        int k = kk * 2 + (tid >> 7), n = tid & 127;
        float v = (k < 64 && n < 100) ? U1[(128 + k) * 100 + n] : 0.f;
        *(unsigned short*)(sm + 32768 + n * 256 + ((k * 2) ^ ((n & 15) << 4))) = f2bf(v);
    }
    __syncthreads();

    // ---- layer 3: frag {wid} < 2 of relu(h2@W3'+b3) -> act (n<64)
    for (int f = wid; f < 2; f += 4) {
        f32x16 acc;
#pragma unroll
        for (int r = 0; r < 16; ++r)
            acc[r] = ((float*)(sm + EB3))[32 * f + (r & 3) + 8 * (r >> 2) + 4 * hi];
#pragma unroll
        for (int ks = 0; ks < 13; ++ks) {
            bf16x8 a = *(const bf16x8*)(sm + (32 * f + l31) * 512 + ((ks * 32 + hi * 16) ^ sw9));
            acc = __builtin_amdgcn_mfma_f32_32x32x16_bf16(a, Bh2[ks], acc, 0, 0, 0);
        }
        act_store(act, l31, f, hi, acc);
    }
    __syncthreads();

    // ---- e = h3 @ U1h + c1 (frag = wid) -> global ; e[100]=1 carrier
    {
        f32x16 ae;
#pragma unroll
        for (int r = 0; r < 16; ++r)
            ae[r] = ((float*)(sm + EC1))[32 * wid + (r & 3) + 8 * (r >> 2) + 4 * hi];
        bf16x8 B4[4];
#pragma unroll
        for (int ks = 0; ks < 4; ++ks) B4[ks] = act_read(act, l31, ks, hi);
#pragma unroll
        for (int ks = 0; ks < 4; ++ks) {
            bf16x8 a = *(const bf16x8*)(sm + 32768 + (32 * wid + l31) * 256 + ((ks * 32 + hi * 16) ^ sw8));
            ae = __builtin_amdgcn_mfma_f32_32x32x16_bf16(a, B4[ks], ae, 0, 0, 0);
        }
#pragma unroll
        for (int r = 0; r < 16; r += 2) {
            int n = 32 * wid + (r & 3) + 8 * (r >> 2) + 4 * hi;
            float v0 = ae[r], v1 = ae[r + 1];
            if (wid == 3 && hi == 1 && r == 0) v0 = 1.f;   // n==100 carrier
            *(unsigned*)(e16 + brow * 128 + n) = pkbf(v0, v1);
        }
    }
}

// ---------------- main fused UMNN kernel (16 waves, barrier-free pipelines) ----
// UNCHANGED from r8 (verified; steady 62us; 64 arch-VGPR + AGPR acc split).
__global__ __launch_bounds__(1024)
__attribute__((amdgpu_waves_per_eu(4, 4))) void umnn_main(
    const float* __restrict__ x,
    const unsigned char* __restrict__ ws, float* __restrict__ out)
{
    __shared__ __align__(16) char sm[SMEM_M];
    float* sX = (float*)(sm + OFF_X);   // [8][128]
    float* sG = (float*)(sm + OFF_G);
    float* sE = (float*)(sm + OFF_E);
    float* sP = (float*)(sm + OFF_P);
    const int tid = threadIdx.x;
    const int lane = tid & 63, wid = tid >> 6;
    const int l31 = lane & 31, hi = lane >> 5;
    const int b8 = blockIdx.x * ROWS_PB;   // grid = 256

    // ---- stage weights (swizzled) + per-row vectors
    {
        const uint4* src = (const uint4*)(ws + WM_OFF);   // 6144 x 16B
        for (int ci = tid; ci < 6144; ci += 1024) {
            int m = ci >> 11, wi = ci & 2047, n = wi >> 4, part = wi & 15;
            uint4 v = src[ci];
            *(uint4*)(sm + m * 32768 + n * 256 + ((part * 16) ^ ((n & 15) << 4))) = v;
        }
        const unsigned short* g16 = (const unsigned short*)(ws + G_OFF);
        const unsigned short* e16 = (const unsigned short*)(ws + E_OFF);
        {
            int r = tid >> 7, d = tid & 127;   // 1024 threads = 8*128
            sX[tid] = x[(b8 + r) * 128 + d];
            sG[tid] = bf2f(g16[(b8 + r) * 128 + d]);
            sE[tid] = bf2f(e16[(b8 + r) * 128 + d]);
        }
    }
    __syncthreads();

    const int row = wid >> 1, half = wid & 1;
    const float* gR = sG + row * 128;
    const float* eR = sE + row * 128;
    const float* xR = sX + row * 128;
    const int sw = (l31 & 15) << 4;
    const char* wB2 = sm;
    const char* wB3 = sm + 32768;
    const char* wB4 = sm + 65536;

    float sumF = 0.f;

#pragma unroll 1
    for (int s = 0; s < 5; ++s) {
        const int t = half * 160 + s * 32 + l31;
        const float tt = ((float)t + 0.5f) * (1.f / 300.f);

        // ---- genA: B[ks] = bf16(relu(tt*g + e)), ks 0..6 (k 112..127 zero)
        bf16x8 B[7];
#pragma unroll
        for (int ks = 0; ks < 7; ++ks) {
            const int k0 = ks * 16 + hi * 8;
            f32x4 g0 = *(const f32x4*)(gR + k0);
            f32x4 g1 = *(const f32x4*)(gR + k0 + 4);
            f32x4 e0 = *(const f32x4*)(eR + k0);
            f32x4 e1 = *(const f32x4*)(eR + k0 + 4);
            float a0 = fmaxf(fmaf(tt, g0[0], e0[0]), 0.f);
            float a1 = fmaxf(fmaf(tt, g0[1], e0[1]), 0.f);
            float a2 = fmaxf(fmaf(tt, g0[2], e0[2]), 0.f);
            float a3 = fmaxf(fmaf(tt, g0[3], e0[3]), 0.f);
            float a4 = fmaxf(fmaf(tt, g1[0], e1[0]), 0.f);
            float a5 = fmaxf(fmaf(tt, g1[1], e1[1]), 0.f);
            float a6 = fmaxf(fmaf(tt, g1[2], e1[2]), 0.f);
            float a7 = fmaxf(fmaf(tt, g1[3], e1[3]), 0.f);
            U4B u;
            u.u[0] = pkbf(a0, a1); u.u[1] = pkbf(a2, a3);
            u.u[2] = pkbf(a4, a5); u.u[3] = pkbf(a6, a7);
            B[ks] = u.v;
        }

        // ---- layers 2 and 3: GEMM + relu + in-register repack
#pragma unroll
        for (int L = 0; L < 2; ++L) {
            const char* wb = (L == 0) ? wB2 : wB3;
            f32x16 acc[4];
#pragma unroll
            for (int f = 0; f < 4; ++f) acc[f] = zero16();
#pragma unroll
            for (int ks = 0; ks < 7; ++ks) {
                const int ko = ks * 32 + hi * 16;
#pragma unroll
                for (int f = 0; f < 4; ++f) {
                    bf16x8 a = *(const bf16x8*)(wb + (32 * f + l31) * 256 + (ko ^ sw));
                    acc[f] = __builtin_amdgcn_mfma_f32_32x32x16_bf16(a, B[ks], acc[f], 0, 0, 0);
                }
            }
#pragma unroll
            for (int f = 0; f < 4; ++f) {
#pragma unroll
                for (int r = 0; r < 16; ++r) acc[f][r] = fmaxf(acc[f][r], 0.f);
                B[2 * f] = packhalf(acc[f], 0);
                if (f < 3) B[2 * f + 1] = packhalf(acc[f], 8);
            }
        }

        // ---- layer 4 + fused elu(p)+1 dot x
        float sdot = 0.f;
#pragma unroll
        for (int f = 0; f < 4; ++f) {
            f32x16 acc = zero16();
#pragma unroll
            for (int ks = 0; ks < 7; ++ks) {
                const int ko = ks * 32 + hi * 16;
                bf16x8 a = *(const bf16x8*)(wB4 + (32 * f + l31) * 256 + (ko ^ sw));
                acc = __builtin_amdgcn_mfma_f32_32x32x16_bf16(a, B[ks], acc, 0, 0, 0);
            }
#pragma unroll
            for (int q = 0; q < 4; ++q) {
                const int n0 = f * 32 + q * 8 + hi * 4;
                f32x4 xv = *(const f32x4*)(xR + n0);
#pragma unroll
                for (int i = 0; i < 4; ++i) {
                    float p = acc[q * 4 + i];
                    float fv = (p > 0.f) ? (p + 1.f) : __expf(p);   // elu+1
                    sdot = fmaf(fv, xv[i], sdot);
                }
            }
        }
        if (t < TSTEPS) sumF += sdot;
    }

    // ---- reduce: wave -> row pairs -> sigmoid
#pragma unroll
    for (int off = 32; off >= 1; off >>= 1) sumF += __shfl_xor(sumF, off);
    if (lane == 0) sP[wid] = sumF;
    __syncthreads();
    if (tid < ROWS_PB) {
        float F = (sP[tid * 2] + sP[tid * 2 + 1]) * (1.f / 300.f);
        out[b8 + tid] = 1.f / (1.f + __expf(-F));
    }
}

// ---------------- launch ----------------
extern "C" void kernel_launch(void* const* d_in, const int* in_sizes, int n_in,
                              void* d_out, int out_size, void* d_ws, size_t ws_size,
                              hipStream_t stream)
{
    const float* x  = (const float*)d_in[0];
    const float* W1 = (const float*)d_in[1];
    const float* b1 = (const float*)d_in[2];
    const float* W2 = (const float*)d_in[3];
    const float* b2 = (const float*)d_in[4];
    const float* W3 = (const float*)d_in[5];
    const float* b3 = (const float*)d_in[6];
    const float* U1 = (const float*)d_in[7];
    const float* c1 = (const float*)d_in[8];
    const float* U2 = (const float*)d_in[9];
    const float* c2 = (const float*)d_in[10];
    const float* U3 = (const float*)d_in[11];
    const float* c3 = (const float*)d_in[12];
    const float* U4 = (const float*)d_in[13];
    const float* c4 = (const float*)d_in[14];
    float* out = (float*)d_out;
    unsigned char* ws = (unsigned char*)d_ws;

    fused_pre<<<72, 256, 0, stream>>>(x, W1, b1, W2, b2, W3, b3, U1, c1,
                                      U2, c2, U3, c3, U4, c4, ws);
    umnn_main<<<BATCH / ROWS_PB, 1024, 0, stream>>>(x, ws, out);
}